// Round 19
// baseline (142.707 us; speedup 1.0000x reference)
//
#include <hip/hip_runtime.h>
#include <hip/hip_bf16.h>

#define D_ 32
#define HID_ 128
#define ROWS 32
#define NCOPY 1024
#define NB_Z 25
#define NB_P 308
#define NB_M 512

typedef __attribute__((ext_vector_type(8))) short bf16x8;
typedef __attribute__((ext_vector_type(4))) float f32x4;
typedef __attribute__((ext_vector_type(4))) unsigned short us4;

__device__ __forceinline__ unsigned short bfh(float v) {
    __hip_bfloat16 b = __float2bfloat16(v);
    unsigned short u;
    __builtin_memcpy(&u, &b, 2);
    return u;
}
__device__ __forceinline__ float bfh2f(unsigned short u) {
    return __uint_as_float(((unsigned)u) << 16);
}
__device__ __forceinline__ float fsig(float x) {
    return __fdividef(1.0f, 1.0f + __expf(-x));
}
__device__ __forceinline__ float ftanh(float x) {
    return 1.0f - __fdividef(2.0f, __expf(2.0f * x) + 1.0f);
}

// ---------------- kA: bm-zero | weight pack (hi+lo) | mean1 partials ----------------
__global__ __launch_bounds__(256) void kA(
    unsigned* __restrict__ bm, int nwords,
    const float* __restrict__ W_gx, const float* __restrict__ W_gh,
    const float* __restrict__ Wz, const float* __restrict__ Vz, const float* __restrict__ Uz,
    const float* __restrict__ Wr, const float* __restrict__ Vr, const float* __restrict__ Ur,
    const float* __restrict__ Wh, const float* __restrict__ Vh, const float* __restrict__ Uh,
    short* __restrict__ gxh, short* __restrict__ gxl,
    short* __restrict__ ghh, short* __restrict__ ghl,
    short* __restrict__ zrh, short* __restrict__ zrl,
    short* __restrict__ h3h, short* __restrict__ h3l,
    const float* __restrict__ X_obs, const float* __restrict__ M_obs,
    float* __restrict__ partials, int n_obs, int chunk)
{
    __shared__ float4 rx[32][9], rm[32][9];
    int bid = blockIdx.x;
    if (bid < NB_Z) {
        int i = bid * 256 + threadIdx.x;
        if (i < nwords) bm[i] = 0u;
        return;
    }
    if (bid < NB_Z + NB_P) {
        int tid = (bid - NB_Z) * 256 + threadIdx.x;
        if (tid >= 78848) return;
        float v = 0.f;
        short* ph;
        short* pl;
        int local;
        if (tid < 1024) {                       // Bgx: K=32, N=32 (B = W_gx^T)
            local = tid;
            int j = local & 7, lane = (local >> 3) & 63, tn = local >> 9;
            int k = ((lane >> 4) << 3) + j;
            int n = tn * 16 + (lane & 15);
            v = W_gx[n * D_ + k];
            ph = gxh; pl = gxl;
        } else if (tid < 5120) {                // Bgh: K=32, N=128 (B = W_gh^T)
            local = tid - 1024;
            int j = local & 7, lane = (local >> 3) & 63, tn = local >> 9;
            int k = ((lane >> 4) << 3) + j;
            int n = tn * 16 + (lane & 15);
            v = W_gh[n * D_ + k];
            ph = ghh; pl = ghl;
        } else if (tid < 54272) {               // Bzr: K=192 [xhat|M|h], N=256 [z|r]
            local = tid - 5120;
            int j = local & 7, lane = (local >> 3) & 63, fs = local >> 9;
            int ks = fs % 6, tn = fs / 6;
            int k = ks * 32 + ((lane >> 4) << 3) + j;
            int n = tn * 16 + (lane & 15);
            const float *W, *V, *U;
            int nc;
            if (n < 128) { W = Wz; V = Vz; U = Uz; nc = n; }
            else         { W = Wr; V = Vr; U = Ur; nc = n - 128; }
            if (k < 32)       v = W[k * HID_ + nc];
            else if (k < 64)  v = V[(k - 32) * HID_ + nc];
            else              v = U[(k - 64) * HID_ + nc];
            ph = zrh; pl = zrl;
        } else {                                // Bh3: K=192 [xhat|M|rh], N=128
            local = tid - 54272;
            int j = local & 7, lane = (local >> 3) & 63, fs = local >> 9;
            int ks = fs % 6, tn = fs / 6;
            int k = ks * 32 + ((lane >> 4) << 3) + j;
            int n = tn * 16 + (lane & 15);
            if (k < 32)       v = Wh[k * HID_ + n];
            else if (k < 64)  v = Vh[(k - 32) * HID_ + n];
            else              v = Uh[(k - 64) * HID_ + n];
            ph = h3h; pl = h3l;
        }
        unsigned short hi = bfh(v);
        unsigned short lo = bfh(v - bfh2f(hi));
        ph[local] = (short)hi;
        pl[local] = (short)lo;
        return;
    }
    // ---- mean1 role: 512 blocks, float4 loads, tree reduce ----
    int mb = bid - (NB_Z + NB_P);
    int start = mb * chunk;
    int end = start + chunk;
    if (end > n_obs) end = n_obs;
    int rq = threadIdx.x >> 3, c4 = threadIdx.x & 7;
    float4 sx = make_float4(0.f, 0.f, 0.f, 0.f);
    float4 sm = sx;
    for (int j = start + rq; j < end; j += 32) {
        float4 xv = ((const float4*)X_obs)[j * 8 + c4];
        float4 mv = ((const float4*)M_obs)[j * 8 + c4];
        sx.x += xv.x; sx.y += xv.y; sx.z += xv.z; sx.w += xv.w;
        sm.x += mv.x + 1e-6f; sm.y += mv.y + 1e-6f; sm.z += mv.z + 1e-6f; sm.w += mv.w + 1e-6f;
    }
    rx[rq][c4] = sx;
    rm[rq][c4] = sm;
    __syncthreads();
    #pragma unroll
    for (int off = 16; off >= 1; off >>= 1) {
        if (rq < off) {
            float4 a = rx[rq][c4], b = rx[rq + off][c4];
            a.x += b.x; a.y += b.y; a.z += b.z; a.w += b.w;
            rx[rq][c4] = a;
            float4 c = rm[rq][c4], d = rm[rq + off][c4];
            c.x += d.x; c.y += d.y; c.z += d.z; c.w += d.w;
            rm[rq][c4] = c;
        }
        __syncthreads();
    }
    if (threadIdx.x < 8) {
        *(float4*)&partials[mb * 64 + threadIdx.x * 4]      = rx[0][threadIdx.x];
        *(float4*)&partials[mb * 64 + 32 + threadIdx.x * 4] = rm[0][threadIdx.x];
    }
}

// ---------------- kB: bitset | mean2 (float4-parallel) ----------------
__global__ __launch_bounds__(256) void kB(
    const int* __restrict__ i_obs, unsigned* __restrict__ bm, int n_obs, int nbB,
    const float* __restrict__ partials, float* __restrict__ mean_x)
{
    __shared__ float4 r4[16][17];
    __shared__ float colsum[64];
    int bid = blockIdx.x;
    if (bid < nbB) {
        int i = bid * 256 + threadIdx.x;
        if (i < n_obs) {
            int gi = i_obs[i];
            atomicOr(&bm[gi >> 5], 1u << (gi & 31));
        }
        return;
    }
    int t = threadIdx.x;
    int cb = t & 15, rg = t >> 4;
    float4 acc = make_float4(0.f, 0.f, 0.f, 0.f);
    const float4* p4 = (const float4*)partials;   // 512 rows x 16 float4
    #pragma unroll 4
    for (int i = 0; i < 32; i++) {
        float4 v = p4[(rg + 16 * i) * 16 + cb];
        acc.x += v.x; acc.y += v.y; acc.z += v.z; acc.w += v.w;
    }
    r4[rg][cb] = acc;
    __syncthreads();
    if (t < 64) {
        float s = 0.f;
        #pragma unroll
        for (int g = 0; g < 16; g++) {
            float4 v = r4[g][t >> 2];
            s += ((const float*)&v)[t & 3];
        }
        colsum[t] = s;
    }
    __syncthreads();
    if (t < 32) mean_x[t] = colsum[t] / colsum[t + 32];
}

// ---------------- fused kernel: mains + copy 3:1; hreg prefetch pre-B1; setprio on GEMMs ----------------
__global__ __launch_bounds__(512, 8) void k_fused(
    const float* __restrict__ ct_p,
    const float* __restrict__ mgn_h,
    const float* __restrict__ X_obs,
    const float* __restrict__ M_obs,
    const int*   __restrict__ i_obs,
    const float* __restrict__ last_x,
    const float* __restrict__ last_t,
    const float* __restrict__ bz, const float* __restrict__ br, const float* __restrict__ bh,
    const float* __restrict__ mean_x,
    const short* __restrict__ gxh, const short* __restrict__ gxl,
    const short* __restrict__ ghh, const short* __restrict__ ghl,
    const short* __restrict__ zrh, const short* __restrict__ zrl,
    const short* __restrict__ h3h, const short* __restrict__ h3l,
    const unsigned* __restrict__ bm,
    float* __restrict__ out_h, float* __restrict__ out_lx, float* __restrict__ out_lt,
    int n_obs, int N, int nblk)
{
    __shared__ unsigned short sh_h[ROWS][136];     // gamma_h * mgn_h
    __shared__ unsigned short sh_rh[ROWS][136];    // r * h
    __shared__ unsigned short sh_iv[ROWS][40];     // interval (bf16)
    __shared__ unsigned short sh_xh[ROWS][40];     // xhat (bf16)
    __shared__ unsigned short sh_M[ROWS][40];
    __shared__ float s_lxn[ROWS][33];
    __shared__ float s_mean[D_];
    __shared__ int   s_idx[ROWS];
    // LDS = 29568 B -> 4 blocks/CU @ 8 waves

    const int t = threadIdx.x;
    const int bid = blockIdx.x;

    // ---- role: every 4th block in the first 4*NCOPY is a copy block (3:1 main:copy per CU) ----
    bool isCopy = false;
    int rid;
    const int inter = 4 * NCOPY;
    if (bid < inter) {
        if ((bid & 3) == 3) { isCopy = true; rid = bid >> 2; }
        else                {                rid = (bid >> 2) * 3 + (bid & 3); }
    } else {
        rid = 3 * NCOPY + (bid - inter);
    }

    if (isCopy) {
        long nh = (long)N * (HID_ / 4);
        long nx = (long)N * (D_ / 4);
        long total = nh + 2 * nx;
        const float4* s_mgn_g = (const float4*)mgn_h;
        const float4* s_lx_g  = (const float4*)last_x;
        const float4* s_lt_g  = (const float4*)last_t;
        float4* d_h  = (float4*)out_h;
        float4* d_lx = (float4*)out_lx;
        float4* d_lt = (float4*)out_lt;
        for (long i = (long)rid * 512 + t; i < total; i += (long)NCOPY * 512) {
            if (i < nh) {
                int row = (int)(i >> 5);
                if (!((bm[row >> 5] >> (row & 31)) & 1u)) d_h[i] = s_mgn_g[i];
            } else if (i < nh + nx) {
                long j = i - nh;
                int row = (int)(j >> 3);
                if (!((bm[row >> 5] >> (row & 31)) & 1u)) d_lx[j] = s_lx_g[j];
            } else {
                long j = i - nh - nx;
                int row = (int)(j >> 3);
                if (!((bm[row >> 5] >> (row & 31)) & 1u)) d_lt[j] = s_lt_g[j];
            }
        }
        return;
    }
    if (rid >= nblk) return;

    const int row0 = rid * ROWS;
    const int wave = t >> 6, lane = t & 63;     // wave 0..7
    const int lo4 = lane & 15, hi2 = lane >> 4;

    if (t < ROWS) {
        int j = row0 + t;
        s_idx[t] = (j < n_obs) ? i_obs[j] : -1;
    }
    if (t >= 64 && t < 96) s_mean[t - 64] = mean_x[t - 64];
    const float ctv = ct_p[0];

    // ---- prefetch mgn_h values this wave will own (direct i_obs loads; overlaps B1) ----
    float hreg[2][4];
    {
        int c = wave * 16 + lo4;
        #pragma unroll
        for (int si = 0; si < 2; si++) {
            #pragma unroll
            for (int q = 0; q < 4; q++) {
                int r = si * 16 + hi2 * 4 + q;
                int j = row0 + r;
                int gi = (j < n_obs) ? i_obs[j] : -1;
                hreg[si][q] = (gi >= 0) ? mgn_h[(long)gi * HID_ + c] : 0.f;
            }
        }
    }
    __syncthreads();                            // B1

    // ---- P1: vectorized pointwise updates (first 256 threads); stage interval/M/lxn ----
    if (t < 256) {
        int rr = t >> 3, c4 = t & 7, d0 = c4 * 4;
        int gi = s_idx[rr];
        float4 Mm = make_float4(0.f, 0.f, 0.f, 0.f);
        float4 itv = Mm, lxn = Mm;
        if (gi >= 0) {
            int j = row0 + rr;
            float4 Xv = ((const float4*)X_obs)[j * 8 + c4];
            Mm = ((const float4*)M_obs)[j * 8 + c4];
            float4 lx = ((const float4*)last_x)[(long)gi * 8 + c4];
            float4 lt = ((const float4*)last_t)[(long)gi * 8 + c4];
            float4 ltn;
            itv.x = ctv - lt.x; lxn.x = lx.x * (1.f - Mm.x) + Xv.x * Mm.x; ltn.x = lt.x * (1.f - Mm.x) + ctv * Mm.x;
            itv.y = ctv - lt.y; lxn.y = lx.y * (1.f - Mm.y) + Xv.y * Mm.y; ltn.y = lt.y * (1.f - Mm.y) + ctv * Mm.y;
            itv.z = ctv - lt.z; lxn.z = lx.z * (1.f - Mm.z) + Xv.z * Mm.z; ltn.z = lt.z * (1.f - Mm.z) + ctv * Mm.z;
            itv.w = ctv - lt.w; lxn.w = lx.w * (1.f - Mm.w) + Xv.w * Mm.w; ltn.w = lt.w * (1.f - Mm.w) + ctv * Mm.w;
            ((float4*)out_lx)[(long)gi * 8 + c4] = lxn;
            ((float4*)out_lt)[(long)gi * 8 + c4] = ltn;
        }
        us4 ih, mh;
        ih.x = bfh(itv.x); mh.x = bfh(Mm.x);
        ih.y = bfh(itv.y); mh.y = bfh(Mm.y);
        ih.z = bfh(itv.z); mh.z = bfh(Mm.z);
        ih.w = bfh(itv.w); mh.w = bfh(Mm.w);
        *(us4*)&sh_iv[rr][d0] = ih;
        *(us4*)&sh_M[rr][d0]  = mh;
        s_lxn[rr][d0 + 0] = lxn.x; s_lxn[rr][d0 + 1] = lxn.y; s_lxn[rr][d0 + 2] = lxn.z; s_lxn[rr][d0 + 3] = lxn.w;
    }
    __syncthreads();                            // B2

    const bf16x8* vgxh = (const bf16x8*)gxh;
    const bf16x8* vgxl = (const bf16x8*)gxl;
    const bf16x8* vghh = (const bf16x8*)ghh;
    const bf16x8* vghl = (const bf16x8*)ghl;
    const bf16x8* vzrh = (const bf16x8*)zrh;
    const bf16x8* vzrl = (const bf16x8*)zrl;
    const bf16x8* vh3h = (const bf16x8*)h3h;
    const bf16x8* vh3l = (const bf16x8*)h3l;

    // ---- P2: gamma_h GEMM (all 8 waves) + gamma_x -> xhat (waves 0,1; separate sh_xh buffer) ----
    {
        bf16x8 bhi = vghh[wave * 64 + lane];
        bf16x8 blo = vghl[wave * 64 + lane];
        int c = wave * 16 + lo4;
        #pragma unroll
        for (int si = 0; si < 2; si++) {
            int ar = si * 16 + lo4;
            bf16x8 ahi = *(const bf16x8*)&sh_iv[ar][hi2 * 8];
            f32x4 acc = {0.f, 0.f, 0.f, 0.f};
            acc = __builtin_amdgcn_mfma_f32_16x16x32_bf16(ahi, bhi, acc, 0, 0, 0);
            acc = __builtin_amdgcn_mfma_f32_16x16x32_bf16(ahi, blo, acc, 0, 0, 0);
            #pragma unroll
            for (int q = 0; q < 4; q++) {
                int r = si * 16 + hi2 * 4 + q;
                float g = __expf(-fmaxf(acc[q], 0.f));
                float hv = g * hreg[si][q];
                hreg[si][q] = hv;
                sh_h[r][c] = bfh(hv);
            }
        }
    }
    if (wave < 2) {
        bf16x8 bhi = vgxh[wave * 64 + lane];
        bf16x8 blo = vgxl[wave * 64 + lane];
        int c = wave * 16 + lo4;
        float mn2 = s_mean[c];
        #pragma unroll
        for (int si = 0; si < 2; si++) {
            int ar = si * 16 + lo4;
            bf16x8 ahi = *(const bf16x8*)&sh_iv[ar][hi2 * 8];
            f32x4 acc = {0.f, 0.f, 0.f, 0.f};
            acc = __builtin_amdgcn_mfma_f32_16x16x32_bf16(ahi, bhi, acc, 0, 0, 0);
            acc = __builtin_amdgcn_mfma_f32_16x16x32_bf16(ahi, blo, acc, 0, 0, 0);
            #pragma unroll
            for (int q = 0; q < 4; q++) {
                int r = si * 16 + hi2 * 4 + q;
                float g = __expf(-fmaxf(acc[q], 0.f));
                float Mv = bfh2f(sh_M[r][c]);
                float lx = s_lxn[r][c];
                float xh = lx * (Mv + (1.f - Mv) * g) + (1.f - Mv) * (1.f - g) * mn2;
                sh_xh[r][c] = bfh(xh);
            }
        }
    }
    __syncthreads();                            // B3

    // ---- P3: z/r GEMM. z tile tn=wave; r tile tn=wave+8; K = 192 ----
    f32x4 accA[2][2];
    #pragma unroll
    for (int ti = 0; ti < 2; ti++)
        #pragma unroll
        for (int si = 0; si < 2; si++)
            accA[ti][si] = (f32x4){0.f, 0.f, 0.f, 0.f};

    __builtin_amdgcn_s_setprio(1);
    #pragma unroll
    for (int ks = 0; ks < 6; ks++) {
        bf16x8 Ah[2];
        #pragma unroll
        for (int si = 0; si < 2; si++) {
            int ar = si * 16 + lo4;
            if (ks == 0)      Ah[si] = *(const bf16x8*)&sh_xh[ar][hi2 * 8];
            else if (ks == 1) Ah[si] = *(const bf16x8*)&sh_M[ar][hi2 * 8];
            else              Ah[si] = *(const bf16x8*)&sh_h[ar][(ks - 2) * 32 + hi2 * 8];
        }
        #pragma unroll
        for (int ti = 0; ti < 2; ti++) {
            int tn = wave + ti * 8;
            int slot = (tn * 6 + ks) * 64 + lane;
            bf16x8 bhi = vzrh[slot];
            bf16x8 blo = vzrl[slot];
            #pragma unroll
            for (int si = 0; si < 2; si++) {
                f32x4 a = accA[ti][si];
                a = __builtin_amdgcn_mfma_f32_16x16x32_bf16(Ah[si], bhi, a, 0, 0, 0);
                a = __builtin_amdgcn_mfma_f32_16x16x32_bf16(Ah[si], blo, a, 0, 0, 0);
                accA[ti][si] = a;
            }
        }
    }
    __builtin_amdgcn_s_setprio(0);
    // activations -> registers; write r*h into separate sh_rh (no pre-barrier needed)
    float zreg[2][4];
    {
        int c = wave * 16 + lo4;
        float bzv = bz[c], brv = br[c];
        #pragma unroll
        for (int si = 0; si < 2; si++) {
            #pragma unroll
            for (int q = 0; q < 4; q++) {
                int r = si * 16 + hi2 * 4 + q;
                zreg[si][q] = fsig(accA[0][si][q] + bzv);
                float rv = fsig(accA[1][si][q] + brv);
                sh_rh[r][c] = bfh(rv * hreg[si][q]);
            }
        }
    }
    __syncthreads();                            // B4

    // ---- P4: h_tilde GEMM (tile tn=wave) + output ----
    f32x4 accB[2];
    #pragma unroll
    for (int si = 0; si < 2; si++)
        accB[si] = (f32x4){0.f, 0.f, 0.f, 0.f};

    __builtin_amdgcn_s_setprio(1);
    #pragma unroll
    for (int ks = 0; ks < 6; ks++) {
        bf16x8 Ah[2];
        #pragma unroll
        for (int si = 0; si < 2; si++) {
            int ar = si * 16 + lo4;
            if (ks == 0)      Ah[si] = *(const bf16x8*)&sh_xh[ar][hi2 * 8];
            else if (ks == 1) Ah[si] = *(const bf16x8*)&sh_M[ar][hi2 * 8];
            else              Ah[si] = *(const bf16x8*)&sh_rh[ar][(ks - 2) * 32 + hi2 * 8];
        }
        int slot = (wave * 6 + ks) * 64 + lane;
        bf16x8 bhi = vh3h[slot];
        bf16x8 blo = vh3l[slot];
        #pragma unroll
        for (int si = 0; si < 2; si++) {
            f32x4 a = accB[si];
            a = __builtin_amdgcn_mfma_f32_16x16x32_bf16(Ah[si], bhi, a, 0, 0, 0);
            a = __builtin_amdgcn_mfma_f32_16x16x32_bf16(Ah[si], blo, a, 0, 0, 0);
            accB[si] = a;
        }
    }
    __builtin_amdgcn_s_setprio(0);
    {
        int c = wave * 16 + lo4;
        float bhv = bh[c];
        #pragma unroll
        for (int si = 0; si < 2; si++) {
            #pragma unroll
            for (int q = 0; q < 4; q++) {
                int r = si * 16 + hi2 * 4 + q;
                int gi = s_idx[r];
                if (gi < 0) continue;
                float ht = ftanh(accB[si][q] + bhv);
                float z  = zreg[si][q];
                out_h[(long)gi * HID_ + c] = (1.f - z) * hreg[si][q] + z * ht;
            }
        }
    }
}

extern "C" void kernel_launch(void* const* d_in, const int* in_sizes, int n_in,
                              void* d_out, int out_size, void* d_ws, size_t ws_size,
                              hipStream_t stream)
{
    const float* ct     = (const float*)d_in[0];
    const float* mgn_h  = (const float*)d_in[1];
    const float* X_obs  = (const float*)d_in[2];
    const float* M_obs  = (const float*)d_in[3];
    const int*   i_obs  = (const int*)d_in[4];
    const float* last_x = (const float*)d_in[5];
    const float* last_t = (const float*)d_in[6];
    const float* W_gx   = (const float*)d_in[7];
    const float* W_gh   = (const float*)d_in[8];
    const float* Wz = (const float*)d_in[9];
    const float* Vz = (const float*)d_in[10];
    const float* Uz = (const float*)d_in[11];
    const float* bz = (const float*)d_in[12];
    const float* Wr = (const float*)d_in[13];
    const float* Vr = (const float*)d_in[14];
    const float* Ur = (const float*)d_in[15];
    const float* br = (const float*)d_in[16];
    const float* Wh = (const float*)d_in[17];
    const float* Vh = (const float*)d_in[18];
    const float* Uh = (const float*)d_in[19];
    const float* bh = (const float*)d_in[20];

    int n_obs = in_sizes[4];
    int N = in_sizes[1] / HID_;

    float* out_h  = (float*)d_out;
    float* out_lx = out_h + (long)N * HID_;
    float* out_lt = out_lx + (long)N * D_;

    char* w = (char*)d_ws;
    float* partials = (float*)w;                       // 512*64*4 = 131072 B
    float* mean_x   = (float*)(w + 131072);            // 128 B
    short* gxh = (short*)(w + 131200);                 // 2048 B
    short* gxl = (short*)(w + 133248);                 // 2048 B
    short* ghh = (short*)(w + 135296);                 // 8192 B
    short* ghl = (short*)(w + 143488);                 // 8192 B
    short* zrh = (short*)(w + 151680);                 // 98304 B
    short* zrl = (short*)(w + 249984);                 // 98304 B
    short* h3h = (short*)(w + 348288);                 // 49152 B
    short* h3l = (short*)(w + 397440);                 // 49152 B
    unsigned* bm = (unsigned*)(w + 446592);            // 25000 B bitmap

    int nwords = (N + 31) / 32;
    int chunk = (n_obs + NB_M - 1) / NB_M;
    kA<<<NB_Z + NB_P + NB_M, 256, 0, stream>>>(
        bm, nwords,
        W_gx, W_gh, Wz, Vz, Uz, Wr, Vr, Ur, Wh, Vh, Uh,
        gxh, gxl, ghh, ghl, zrh, zrl, h3h, h3l,
        X_obs, M_obs, partials, n_obs, chunk);

    int nbB = (n_obs + 255) / 256;
    kB<<<nbB + 1, 256, 0, stream>>>(i_obs, bm, n_obs, nbB, partials, mean_x);

    int nblk = (n_obs + ROWS - 1) / ROWS;
    int grid = (nblk > 3 * NCOPY) ? (nblk + NCOPY) : (4 * NCOPY);
    k_fused<<<grid, 512, 0, stream>>>(
        ct, mgn_h, X_obs, M_obs, i_obs, last_x, last_t,
        bz, br, bh, mean_x,
        gxh, gxl, ghh, ghl, zrh, zrl, h3h, h3l,
        bm, out_h, out_lx, out_lt, n_obs, N, nblk);
}

// Round 20
// 131.284 us; speedup vs baseline: 1.0870x; 1.0870x over previous
//
#include <hip/hip_runtime.h>
#include <hip/hip_bf16.h>

#define D_ 32
#define HID_ 128
#define ROWS 32
#define NCOPY 1024
#define NB_Z 25
#define NB_P 308
#define NB_M 512

typedef __attribute__((ext_vector_type(8))) short bf16x8;
typedef __attribute__((ext_vector_type(4))) float f32x4;
typedef __attribute__((ext_vector_type(4))) unsigned short us4;

__device__ __forceinline__ unsigned short bfh(float v) {
    __hip_bfloat16 b = __float2bfloat16(v);
    unsigned short u;
    __builtin_memcpy(&u, &b, 2);
    return u;
}
__device__ __forceinline__ float bfh2f(unsigned short u) {
    return __uint_as_float(((unsigned)u) << 16);
}
__device__ __forceinline__ float fsig(float x) {
    return __fdividef(1.0f, 1.0f + __expf(-x));
}
__device__ __forceinline__ float ftanh(float x) {
    return 1.0f - __fdividef(2.0f, __expf(2.0f * x) + 1.0f);
}

// ---------------- kA: bm-zero | weight pack (hi+lo) | mean1 partials ----------------
__global__ __launch_bounds__(256) void kA(
    unsigned* __restrict__ bm, int nwords,
    const float* __restrict__ W_gx, const float* __restrict__ W_gh,
    const float* __restrict__ Wz, const float* __restrict__ Vz, const float* __restrict__ Uz,
    const float* __restrict__ Wr, const float* __restrict__ Vr, const float* __restrict__ Ur,
    const float* __restrict__ Wh, const float* __restrict__ Vh, const float* __restrict__ Uh,
    short* __restrict__ gxh, short* __restrict__ gxl,
    short* __restrict__ ghh, short* __restrict__ ghl,
    short* __restrict__ zrh, short* __restrict__ zrl,
    short* __restrict__ h3h, short* __restrict__ h3l,
    const float* __restrict__ X_obs, const float* __restrict__ M_obs,
    float* __restrict__ partials, int n_obs, int chunk)
{
    __shared__ float4 rx[32][9], rm[32][9];
    int bid = blockIdx.x;
    if (bid < NB_Z) {
        int i = bid * 256 + threadIdx.x;
        if (i < nwords) bm[i] = 0u;
        return;
    }
    if (bid < NB_Z + NB_P) {
        int tid = (bid - NB_Z) * 256 + threadIdx.x;
        if (tid >= 78848) return;
        float v = 0.f;
        short* ph;
        short* pl;
        int local;
        if (tid < 1024) {                       // Bgx: K=32, N=32 (B = W_gx^T)
            local = tid;
            int j = local & 7, lane = (local >> 3) & 63, tn = local >> 9;
            int k = ((lane >> 4) << 3) + j;
            int n = tn * 16 + (lane & 15);
            v = W_gx[n * D_ + k];
            ph = gxh; pl = gxl;
        } else if (tid < 5120) {                // Bgh: K=32, N=128 (B = W_gh^T)
            local = tid - 1024;
            int j = local & 7, lane = (local >> 3) & 63, tn = local >> 9;
            int k = ((lane >> 4) << 3) + j;
            int n = tn * 16 + (lane & 15);
            v = W_gh[n * D_ + k];
            ph = ghh; pl = ghl;
        } else if (tid < 54272) {               // Bzr: K=192 [xhat|M|h], N=256 [z|r]
            local = tid - 5120;
            int j = local & 7, lane = (local >> 3) & 63, fs = local >> 9;
            int ks = fs % 6, tn = fs / 6;
            int k = ks * 32 + ((lane >> 4) << 3) + j;
            int n = tn * 16 + (lane & 15);
            const float *W, *V, *U;
            int nc;
            if (n < 128) { W = Wz; V = Vz; U = Uz; nc = n; }
            else         { W = Wr; V = Vr; U = Ur; nc = n - 128; }
            if (k < 32)       v = W[k * HID_ + nc];
            else if (k < 64)  v = V[(k - 32) * HID_ + nc];
            else              v = U[(k - 64) * HID_ + nc];
            ph = zrh; pl = zrl;
        } else {                                // Bh3: K=192 [xhat|M|rh], N=128
            local = tid - 54272;
            int j = local & 7, lane = (local >> 3) & 63, fs = local >> 9;
            int ks = fs % 6, tn = fs / 6;
            int k = ks * 32 + ((lane >> 4) << 3) + j;
            int n = tn * 16 + (lane & 15);
            if (k < 32)       v = Wh[k * HID_ + n];
            else if (k < 64)  v = Vh[(k - 32) * HID_ + n];
            else              v = Uh[(k - 64) * HID_ + n];
            ph = h3h; pl = h3l;
        }
        unsigned short hi = bfh(v);
        unsigned short lo = bfh(v - bfh2f(hi));
        ph[local] = (short)hi;
        pl[local] = (short)lo;
        return;
    }
    // ---- mean1 role: 512 blocks, float4 loads, tree reduce ----
    int mb = bid - (NB_Z + NB_P);
    int start = mb * chunk;
    int end = start + chunk;
    if (end > n_obs) end = n_obs;
    int rq = threadIdx.x >> 3, c4 = threadIdx.x & 7;
    float4 sx = make_float4(0.f, 0.f, 0.f, 0.f);
    float4 sm = sx;
    for (int j = start + rq; j < end; j += 32) {
        float4 xv = ((const float4*)X_obs)[j * 8 + c4];
        float4 mv = ((const float4*)M_obs)[j * 8 + c4];
        sx.x += xv.x; sx.y += xv.y; sx.z += xv.z; sx.w += xv.w;
        sm.x += mv.x + 1e-6f; sm.y += mv.y + 1e-6f; sm.z += mv.z + 1e-6f; sm.w += mv.w + 1e-6f;
    }
    rx[rq][c4] = sx;
    rm[rq][c4] = sm;
    __syncthreads();
    #pragma unroll
    for (int off = 16; off >= 1; off >>= 1) {
        if (rq < off) {
            float4 a = rx[rq][c4], b = rx[rq + off][c4];
            a.x += b.x; a.y += b.y; a.z += b.z; a.w += b.w;
            rx[rq][c4] = a;
            float4 c = rm[rq][c4], d = rm[rq + off][c4];
            c.x += d.x; c.y += d.y; c.z += d.z; c.w += d.w;
            rm[rq][c4] = c;
        }
        __syncthreads();
    }
    if (threadIdx.x < 8) {
        *(float4*)&partials[mb * 64 + threadIdx.x * 4]      = rx[0][threadIdx.x];
        *(float4*)&partials[mb * 64 + 32 + threadIdx.x * 4] = rm[0][threadIdx.x];
    }
}

// ---------------- kB: bitset | mean2 (float4-parallel) ----------------
__global__ __launch_bounds__(256) void kB(
    const int* __restrict__ i_obs, unsigned* __restrict__ bm, int n_obs, int nbB,
    const float* __restrict__ partials, float* __restrict__ mean_x)
{
    __shared__ float4 r4[16][17];
    __shared__ float colsum[64];
    int bid = blockIdx.x;
    if (bid < nbB) {
        int i = bid * 256 + threadIdx.x;
        if (i < n_obs) {
            int gi = i_obs[i];
            atomicOr(&bm[gi >> 5], 1u << (gi & 31));
        }
        return;
    }
    int t = threadIdx.x;
    int cb = t & 15, rg = t >> 4;
    float4 acc = make_float4(0.f, 0.f, 0.f, 0.f);
    const float4* p4 = (const float4*)partials;   // 512 rows x 16 float4
    #pragma unroll 4
    for (int i = 0; i < 32; i++) {
        float4 v = p4[(rg + 16 * i) * 16 + cb];
        acc.x += v.x; acc.y += v.y; acc.z += v.z; acc.w += v.w;
    }
    r4[rg][cb] = acc;
    __syncthreads();
    if (t < 64) {
        float s = 0.f;
        #pragma unroll
        for (int g = 0; g < 16; g++) {
            float4 v = r4[g][t >> 2];
            s += ((const float*)&v)[t & 3];
        }
        colsum[t] = s;
    }
    __syncthreads();
    if (t < 32) mean_x[t] = colsum[t] / colsum[t + 32];
}

// ---------------- fused kernel: mains + copy 3:1; bf16-hi A; 4-barrier phase chain ----------------
__global__ __launch_bounds__(512, 8) void k_fused(
    const float* __restrict__ ct_p,
    const float* __restrict__ mgn_h,
    const float* __restrict__ X_obs,
    const float* __restrict__ M_obs,
    const int*   __restrict__ i_obs,
    const float* __restrict__ last_x,
    const float* __restrict__ last_t,
    const float* __restrict__ bz, const float* __restrict__ br, const float* __restrict__ bh,
    const float* __restrict__ mean_x,
    const short* __restrict__ gxh, const short* __restrict__ gxl,
    const short* __restrict__ ghh, const short* __restrict__ ghl,
    const short* __restrict__ zrh, const short* __restrict__ zrl,
    const short* __restrict__ h3h, const short* __restrict__ h3l,
    const unsigned* __restrict__ bm,
    float* __restrict__ out_h, float* __restrict__ out_lx, float* __restrict__ out_lt,
    int n_obs, int N, int nblk)
{
    __shared__ unsigned short sh_h[ROWS][136];     // gamma_h * mgn_h
    __shared__ unsigned short sh_rh[ROWS][136];    // r * h
    __shared__ unsigned short sh_iv[ROWS][40];     // interval (bf16)
    __shared__ unsigned short sh_xh[ROWS][40];     // xhat (bf16)
    __shared__ unsigned short sh_M[ROWS][40];
    __shared__ float s_lxn[ROWS][33];
    __shared__ float s_mean[D_];
    __shared__ int   s_idx[ROWS];
    // LDS = 29568 B -> 4 blocks/CU @ 8 waves

    const int t = threadIdx.x;
    const int bid = blockIdx.x;

    // ---- role: every 4th block in the first 4*NCOPY is a copy block (3:1 main:copy per CU) ----
    bool isCopy = false;
    int rid;
    const int inter = 4 * NCOPY;
    if (bid < inter) {
        if ((bid & 3) == 3) { isCopy = true; rid = bid >> 2; }
        else                {                rid = (bid >> 2) * 3 + (bid & 3); }
    } else {
        rid = 3 * NCOPY + (bid - inter);
    }

    if (isCopy) {
        long nh = (long)N * (HID_ / 4);
        long nx = (long)N * (D_ / 4);
        long total = nh + 2 * nx;
        const float4* s_mgn_g = (const float4*)mgn_h;
        const float4* s_lx_g  = (const float4*)last_x;
        const float4* s_lt_g  = (const float4*)last_t;
        float4* d_h  = (float4*)out_h;
        float4* d_lx = (float4*)out_lx;
        float4* d_lt = (float4*)out_lt;
        for (long i = (long)rid * 512 + t; i < total; i += (long)NCOPY * 512) {
            if (i < nh) {
                int row = (int)(i >> 5);
                if (!((bm[row >> 5] >> (row & 31)) & 1u)) d_h[i] = s_mgn_g[i];
            } else if (i < nh + nx) {
                long j = i - nh;
                int row = (int)(j >> 3);
                if (!((bm[row >> 5] >> (row & 31)) & 1u)) d_lx[j] = s_lx_g[j];
            } else {
                long j = i - nh - nx;
                int row = (int)(j >> 3);
                if (!((bm[row >> 5] >> (row & 31)) & 1u)) d_lt[j] = s_lt_g[j];
            }
        }
        return;
    }
    if (rid >= nblk) return;

    const int row0 = rid * ROWS;
    const int wave = t >> 6, lane = t & 63;     // wave 0..7
    const int lo4 = lane & 15, hi2 = lane >> 4;

    if (t < ROWS) {
        int j = row0 + t;
        s_idx[t] = (j < n_obs) ? i_obs[j] : -1;
    }
    if (t >= 64 && t < 96) s_mean[t - 64] = mean_x[t - 64];
    __syncthreads();                            // B1
    const float ctv = ct_p[0];

    // ---- prefetch mgn_h values this wave will own (cols of tile tn=wave) ----
    float hreg[2][4];
    {
        int c = wave * 16 + lo4;
        #pragma unroll
        for (int si = 0; si < 2; si++) {
            #pragma unroll
            for (int q = 0; q < 4; q++) {
                int r = si * 16 + hi2 * 4 + q;
                int gi = s_idx[r];
                hreg[si][q] = (gi >= 0) ? mgn_h[(long)gi * HID_ + c] : 0.f;
            }
        }
    }

    // ---- P1: vectorized pointwise updates (first 256 threads); stage interval/M/lxn ----
    if (t < 256) {
        int rr = t >> 3, c4 = t & 7, d0 = c4 * 4;
        int gi = s_idx[rr];
        float4 Mm = make_float4(0.f, 0.f, 0.f, 0.f);
        float4 itv = Mm, lxn = Mm;
        if (gi >= 0) {
            int j = row0 + rr;
            float4 Xv = ((const float4*)X_obs)[j * 8 + c4];
            Mm = ((const float4*)M_obs)[j * 8 + c4];
            float4 lx = ((const float4*)last_x)[(long)gi * 8 + c4];
            float4 lt = ((const float4*)last_t)[(long)gi * 8 + c4];
            float4 ltn;
            itv.x = ctv - lt.x; lxn.x = lx.x * (1.f - Mm.x) + Xv.x * Mm.x; ltn.x = lt.x * (1.f - Mm.x) + ctv * Mm.x;
            itv.y = ctv - lt.y; lxn.y = lx.y * (1.f - Mm.y) + Xv.y * Mm.y; ltn.y = lt.y * (1.f - Mm.y) + ctv * Mm.y;
            itv.z = ctv - lt.z; lxn.z = lx.z * (1.f - Mm.z) + Xv.z * Mm.z; ltn.z = lt.z * (1.f - Mm.z) + ctv * Mm.z;
            itv.w = ctv - lt.w; lxn.w = lx.w * (1.f - Mm.w) + Xv.w * Mm.w; ltn.w = lt.w * (1.f - Mm.w) + ctv * Mm.w;
            ((float4*)out_lx)[(long)gi * 8 + c4] = lxn;
            ((float4*)out_lt)[(long)gi * 8 + c4] = ltn;
        }
        us4 ih, mh;
        ih.x = bfh(itv.x); mh.x = bfh(Mm.x);
        ih.y = bfh(itv.y); mh.y = bfh(Mm.y);
        ih.z = bfh(itv.z); mh.z = bfh(Mm.z);
        ih.w = bfh(itv.w); mh.w = bfh(Mm.w);
        *(us4*)&sh_iv[rr][d0] = ih;
        *(us4*)&sh_M[rr][d0]  = mh;
        s_lxn[rr][d0 + 0] = lxn.x; s_lxn[rr][d0 + 1] = lxn.y; s_lxn[rr][d0 + 2] = lxn.z; s_lxn[rr][d0 + 3] = lxn.w;
    }
    __syncthreads();                            // B2

    const bf16x8* vgxh = (const bf16x8*)gxh;
    const bf16x8* vgxl = (const bf16x8*)gxl;
    const bf16x8* vghh = (const bf16x8*)ghh;
    const bf16x8* vghl = (const bf16x8*)ghl;
    const bf16x8* vzrh = (const bf16x8*)zrh;
    const bf16x8* vzrl = (const bf16x8*)zrl;
    const bf16x8* vh3h = (const bf16x8*)h3h;
    const bf16x8* vh3l = (const bf16x8*)h3l;

    // ---- P2: gamma_h GEMM (all 8 waves) + gamma_x -> xhat (waves 0,1; separate sh_xh buffer) ----
    {
        bf16x8 bhi = vghh[wave * 64 + lane];
        bf16x8 blo = vghl[wave * 64 + lane];
        int c = wave * 16 + lo4;
        #pragma unroll
        for (int si = 0; si < 2; si++) {
            int ar = si * 16 + lo4;
            bf16x8 ahi = *(const bf16x8*)&sh_iv[ar][hi2 * 8];
            f32x4 acc = {0.f, 0.f, 0.f, 0.f};
            acc = __builtin_amdgcn_mfma_f32_16x16x32_bf16(ahi, bhi, acc, 0, 0, 0);
            acc = __builtin_amdgcn_mfma_f32_16x16x32_bf16(ahi, blo, acc, 0, 0, 0);
            #pragma unroll
            for (int q = 0; q < 4; q++) {
                int r = si * 16 + hi2 * 4 + q;
                float g = __expf(-fmaxf(acc[q], 0.f));
                float hv = g * hreg[si][q];
                hreg[si][q] = hv;
                sh_h[r][c] = bfh(hv);
            }
        }
    }
    if (wave < 2) {
        bf16x8 bhi = vgxh[wave * 64 + lane];
        bf16x8 blo = vgxl[wave * 64 + lane];
        int c = wave * 16 + lo4;
        float mn2 = s_mean[c];
        #pragma unroll
        for (int si = 0; si < 2; si++) {
            int ar = si * 16 + lo4;
            bf16x8 ahi = *(const bf16x8*)&sh_iv[ar][hi2 * 8];
            f32x4 acc = {0.f, 0.f, 0.f, 0.f};
            acc = __builtin_amdgcn_mfma_f32_16x16x32_bf16(ahi, bhi, acc, 0, 0, 0);
            acc = __builtin_amdgcn_mfma_f32_16x16x32_bf16(ahi, blo, acc, 0, 0, 0);
            #pragma unroll
            for (int q = 0; q < 4; q++) {
                int r = si * 16 + hi2 * 4 + q;
                float g = __expf(-fmaxf(acc[q], 0.f));
                float Mv = bfh2f(sh_M[r][c]);
                float lx = s_lxn[r][c];
                float xh = lx * (Mv + (1.f - Mv) * g) + (1.f - Mv) * (1.f - g) * mn2;
                sh_xh[r][c] = bfh(xh);
            }
        }
    }
    __syncthreads();                            // B3

    // ---- P3: z/r GEMM. z tile tn=wave; r tile tn=wave+8; K = 192 ----
    f32x4 accA[2][2];
    #pragma unroll
    for (int ti = 0; ti < 2; ti++)
        #pragma unroll
        for (int si = 0; si < 2; si++)
            accA[ti][si] = (f32x4){0.f, 0.f, 0.f, 0.f};

    #pragma unroll
    for (int ks = 0; ks < 6; ks++) {
        bf16x8 Ah[2];
        #pragma unroll
        for (int si = 0; si < 2; si++) {
            int ar = si * 16 + lo4;
            if (ks == 0)      Ah[si] = *(const bf16x8*)&sh_xh[ar][hi2 * 8];
            else if (ks == 1) Ah[si] = *(const bf16x8*)&sh_M[ar][hi2 * 8];
            else              Ah[si] = *(const bf16x8*)&sh_h[ar][(ks - 2) * 32 + hi2 * 8];
        }
        #pragma unroll
        for (int ti = 0; ti < 2; ti++) {
            int tn = wave + ti * 8;
            int slot = (tn * 6 + ks) * 64 + lane;
            bf16x8 bhi = vzrh[slot];
            bf16x8 blo = vzrl[slot];
            #pragma unroll
            for (int si = 0; si < 2; si++) {
                f32x4 a = accA[ti][si];
                a = __builtin_amdgcn_mfma_f32_16x16x32_bf16(Ah[si], bhi, a, 0, 0, 0);
                a = __builtin_amdgcn_mfma_f32_16x16x32_bf16(Ah[si], blo, a, 0, 0, 0);
                accA[ti][si] = a;
            }
        }
    }
    // activations -> registers; write r*h into separate sh_rh (no pre-barrier needed)
    float zreg[2][4];
    {
        int c = wave * 16 + lo4;
        float bzv = bz[c], brv = br[c];
        #pragma unroll
        for (int si = 0; si < 2; si++) {
            #pragma unroll
            for (int q = 0; q < 4; q++) {
                int r = si * 16 + hi2 * 4 + q;
                zreg[si][q] = fsig(accA[0][si][q] + bzv);
                float rv = fsig(accA[1][si][q] + brv);
                sh_rh[r][c] = bfh(rv * hreg[si][q]);
            }
        }
    }
    __syncthreads();                            // B4

    // ---- P4: h_tilde GEMM (tile tn=wave) + output ----
    f32x4 accB[2];
    #pragma unroll
    for (int si = 0; si < 2; si++)
        accB[si] = (f32x4){0.f, 0.f, 0.f, 0.f};

    #pragma unroll
    for (int ks = 0; ks < 6; ks++) {
        bf16x8 Ah[2];
        #pragma unroll
        for (int si = 0; si < 2; si++) {
            int ar = si * 16 + lo4;
            if (ks == 0)      Ah[si] = *(const bf16x8*)&sh_xh[ar][hi2 * 8];
            else if (ks == 1) Ah[si] = *(const bf16x8*)&sh_M[ar][hi2 * 8];
            else              Ah[si] = *(const bf16x8*)&sh_rh[ar][(ks - 2) * 32 + hi2 * 8];
        }
        int slot = (wave * 6 + ks) * 64 + lane;
        bf16x8 bhi = vh3h[slot];
        bf16x8 blo = vh3l[slot];
        #pragma unroll
        for (int si = 0; si < 2; si++) {
            f32x4 a = accB[si];
            a = __builtin_amdgcn_mfma_f32_16x16x32_bf16(Ah[si], bhi, a, 0, 0, 0);
            a = __builtin_amdgcn_mfma_f32_16x16x32_bf16(Ah[si], blo, a, 0, 0, 0);
            accB[si] = a;
        }
    }
    {
        int c = wave * 16 + lo4;
        float bhv = bh[c];
        #pragma unroll
        for (int si = 0; si < 2; si++) {
            #pragma unroll
            for (int q = 0; q < 4; q++) {
                int r = si * 16 + hi2 * 4 + q;
                int gi = s_idx[r];
                if (gi < 0) continue;
                float ht = ftanh(accB[si][q] + bhv);
                float z  = zreg[si][q];
                out_h[(long)gi * HID_ + c] = (1.f - z) * hreg[si][q] + z * ht;
            }
        }
    }
}

extern "C" void kernel_launch(void* const* d_in, const int* in_sizes, int n_in,
                              void* d_out, int out_size, void* d_ws, size_t ws_size,
                              hipStream_t stream)
{
    const float* ct     = (const float*)d_in[0];
    const float* mgn_h  = (const float*)d_in[1];
    const float* X_obs  = (const float*)d_in[2];
    const float* M_obs  = (const float*)d_in[3];
    const int*   i_obs  = (const int*)d_in[4];
    const float* last_x = (const float*)d_in[5];
    const float* last_t = (const float*)d_in[6];
    const float* W_gx   = (const float*)d_in[7];
    const float* W_gh   = (const float*)d_in[8];
    const float* Wz = (const float*)d_in[9];
    const float* Vz = (const float*)d_in[10];
    const float* Uz = (const float*)d_in[11];
    const float* bz = (const float*)d_in[12];
    const float* Wr = (const float*)d_in[13];
    const float* Vr = (const float*)d_in[14];
    const float* Ur = (const float*)d_in[15];
    const float* br = (const float*)d_in[16];
    const float* Wh = (const float*)d_in[17];
    const float* Vh = (const float*)d_in[18];
    const float* Uh = (const float*)d_in[19];
    const float* bh = (const float*)d_in[20];

    int n_obs = in_sizes[4];
    int N = in_sizes[1] / HID_;

    float* out_h  = (float*)d_out;
    float* out_lx = out_h + (long)N * HID_;
    float* out_lt = out_lx + (long)N * D_;

    char* w = (char*)d_ws;
    float* partials = (float*)w;                       // 512*64*4 = 131072 B
    float* mean_x   = (float*)(w + 131072);            // 128 B
    short* gxh = (short*)(w + 131200);                 // 2048 B
    short* gxl = (short*)(w + 133248);                 // 2048 B
    short* ghh = (short*)(w + 135296);                 // 8192 B
    short* ghl = (short*)(w + 143488);                 // 8192 B
    short* zrh = (short*)(w + 151680);                 // 98304 B
    short* zrl = (short*)(w + 249984);                 // 98304 B
    short* h3h = (short*)(w + 348288);                 // 49152 B
    short* h3l = (short*)(w + 397440);                 // 49152 B
    unsigned* bm = (unsigned*)(w + 446592);            // 25000 B bitmap

    int nwords = (N + 31) / 32;
    int chunk = (n_obs + NB_M - 1) / NB_M;
    kA<<<NB_Z + NB_P + NB_M, 256, 0, stream>>>(
        bm, nwords,
        W_gx, W_gh, Wz, Vz, Uz, Wr, Vr, Ur, Wh, Vh, Uh,
        gxh, gxl, ghh, ghl, zrh, zrl, h3h, h3l,
        X_obs, M_obs, partials, n_obs, chunk);

    int nbB = (n_obs + 255) / 256;
    kB<<<nbB + 1, 256, 0, stream>>>(i_obs, bm, n_obs, nbB, partials, mean_x);

    int nblk = (n_obs + ROWS - 1) / ROWS;
    int grid = (nblk > 3 * NCOPY) ? (nblk + NCOPY) : (4 * NCOPY);
    k_fused<<<grid, 512, 0, stream>>>(
        ct, mgn_h, X_obs, M_obs, i_obs, last_x, last_t,
        bz, br, bh, mean_x,
        gxh, gxl, ghh, ghl, zrh, zrl, h3h, h3l,
        bm, out_h, out_lx, out_lt, n_obs, N, nblk);
}